// Round 7
// baseline (310.265 us; speedup 1.0000x reference)
//
#include <hip/hip_runtime.h>
#include <hip/hip_bf16.h>

#define FDIM 256
#define NATOMS 64

using bf16x8 = __attribute__((ext_vector_type(8))) short;
using f32x4  = __attribute__((ext_vector_type(4))) float;

__device__ __forceinline__ float fast_sigm(float x) {
    return __builtin_amdgcn_rcpf(1.0f + __expf(-x));
}
__device__ __forceinline__ unsigned cvt_pk_bf16(float lo, float hi) {
    unsigned r;
    asm("v_cvt_pk_bf16_f32 %0, %1, %2" : "=v"(r) : "v"(lo), "v"(hi));
    return r;
}

// ---------------- prep 1: wk± = W_lin @ k±, bk± = b_lin . k± ----------------
__global__ void prep_wk(const float* __restrict__ W_lin, const float* __restrict__ b_lin,
                        const float* __restrict__ kp, const float* __restrict__ km,
                        float* __restrict__ wkp, float* __restrict__ wkm,
                        float* __restrict__ bk2) {
    const int f = blockIdx.x;
    const int t = threadIdx.x;
    __shared__ float sp[FDIM], sm[FDIM];
    float w = W_lin[(size_t)f * FDIM + t];
    sp[t] = w * kp[t];
    sm[t] = w * km[t];
    __syncthreads();
    for (int s = 128; s > 0; s >>= 1) {
        if (t < s) { sp[t] += sp[t + s]; sm[t] += sm[t + s]; }
        __syncthreads();
    }
    if (t == 0) { wkp[f] = sp[0]; wkm[f] = sm[0]; }
    if (f == 0) {
        __syncthreads();
        sp[t] = b_lin[t] * kp[t];
        sm[t] = b_lin[t] * km[t];
        __syncthreads();
        for (int s = 128; s > 0; s >>= 1) {
            if (t < s) { sp[t] += sp[t + s]; sm[t] += sm[t + s]; }
            __syncthreads();
        }
        if (t == 0) { bk2[0] = sp[0]; bk2[1] = sm[0]; }
    }
}

// ---------------- prep 2: Wt[n][k] = bf16(W[k][n]) ----------------
__global__ void prep_wt(const float* __restrict__ W1, const float* __restrict__ W2,
                        const float* __restrict__ W3,
                        __hip_bfloat16* __restrict__ Wt1, __hip_bfloat16* __restrict__ Wt2,
                        __hip_bfloat16* __restrict__ Wt3) {
    const int b = blockIdx.x;
    const int mat = b >> 8;
    const int n = b & 255;
    const int k = threadIdx.x;
    const float* W = (mat == 0) ? W1 : (mat == 1) ? W2 : W3;
    __hip_bfloat16* Wt = (mat == 0) ? Wt1 : (mat == 1) ? Wt2 : Wt3;
    Wt[(size_t)n * FDIM + k] = __float2bfloat16(W[(size_t)k * FDIM + n]);
}

// ---------------- fused: 2 molecules / block, 4 waves ----------------
// Wave (p, fh): molecule p (of 2), feature-half fh (128 feats) x 64 atoms.
// X stored XOR-swizzled (16B granule, chunk ^= row&15) -> conflict-free b128.
__global__ __launch_bounds__(256, 2) void fused_ee(
    const float* __restrict__ psi, const float* __restrict__ e_z,
    const float* __restrict__ wkp, const float* __restrict__ wkm,
    const float* __restrict__ bk2,
    const float* __restrict__ vp, const float* __restrict__ vm,
    const __hip_bfloat16* __restrict__ Wt1, const __hip_bfloat16* __restrict__ Wt2,
    const __hip_bfloat16* __restrict__ Wt3,
    const float* __restrict__ a1g, const float* __restrict__ be1g,
    const float* __restrict__ a2g, const float* __restrict__ be2g,
    const float* __restrict__ a3g, const float* __restrict__ be3g,
    const float* __restrict__ b_out, float* __restrict__ out) {

    // X[p][row][512 bytes], swizzled: byte(row, col2B) =
    //   row*512 + ((chunk16 ^ (row&15))<<4) + (col2B*2 & 15)
    __shared__ unsigned char Xb[2][NATOMS][512];
    __shared__ float nums[2][NATOMS];

    const int tid = threadIdx.x;
    const int lane = tid & 63;
    const int wv = tid >> 6;       // 0..3
    const int p = wv >> 1;         // molecule select
    const int half = wv & 1;       // atom-half for producer phases
    const int fh = wv & 1;         // feature-half for GEMM
    const int l15 = lane & 15;
    const int hi4 = lane >> 4;     // 0..3
    const int mol = blockIdx.x * 2 + p;
    const float psiv = psi[mol];
    const bool pos = (psiv >= 0.0f);
    unsigned char* xbp = &Xb[p][0][0];

    // ---- attention dots: 32 rows per wave, 2 batches of 16 batched loads ----
    {
        const float4 wkv = pos ? reinterpret_cast<const float4*>(wkp)[lane]
                               : reinterpret_cast<const float4*>(wkm)[lane];
        const float bk = pos ? bk2[0] : bk2[1];
        const float4* ez4 = reinterpret_cast<const float4*>(e_z + (size_t)mol * NATOMS * FDIM);
#pragma unroll
        for (int b = 0; b < 2; ++b) {
            const int r0 = half * 32 + b * 16;
            float4 ev[16];
#pragma unroll
            for (int i = 0; i < 16; ++i) ev[i] = ez4[(size_t)(r0 + i) * 64 + lane];
#pragma unroll
            for (int i = 0; i < 16; ++i) {
                float d = ev[i].x * wkv.x + ev[i].y * wkv.y + ev[i].z * wkv.z + ev[i].w * wkv.w;
#pragma unroll
                for (int off = 32; off > 0; off >>= 1) d += __shfl_xor(d, off, 64);
                if (lane == 0) nums[p][r0 + i] = (d + bk) * 0.0625f;
            }
        }
    }
    __syncthreads();

    // ---- per-wave softmax over this wave's molecule ----
    float aL_reg;  // a_i for atom == lane, molecule p
    {
        float arg = nums[p][lane];
        float nv = fmaxf(arg, 0.0f) + log1pf(__expf(-fabsf(arg)));
        float s = nv;
#pragma unroll
        for (int off = 32; off > 0; off >>= 1) s += __shfl_xor(s, off, 64);
        aL_reg = psiv * nv * __builtin_amdgcn_rcpf(s);
    }

    // ---- stage-1 input: X[p][r][c] = bf16(swish1(a_r * v_c)), rows half*32..+32 ----
    {
        const float4 v4  = pos ? reinterpret_cast<const float4*>(vp)[lane]
                               : reinterpret_cast<const float4*>(vm)[lane];
        const float4 a14 = reinterpret_cast<const float4*>(a1g)[lane];
        const float4 b14 = reinterpret_cast<const float4*>(be1g)[lane];
        const int wchunk = lane >> 1;        // 16B chunk of this lane's 8B write
        const int woff = (lane & 1) << 3;    // 8B half within chunk
#pragma unroll
        for (int i = 0; i < 32; ++i) {
            const int r = half * 32 + i;
            const float al = __shfl(aL_reg, r, 64);
            float x0 = al * v4.x, x1 = al * v4.y, x2 = al * v4.z, x3 = al * v4.w;
            uint2 pk;
            pk.x = cvt_pk_bf16(a14.x * x0 * fast_sigm(b14.x * x0),
                               a14.y * x1 * fast_sigm(b14.y * x1));
            pk.y = cvt_pk_bf16(a14.z * x2 * fast_sigm(b14.z * x2),
                               a14.w * x3 * fast_sigm(b14.w * x3));
            *reinterpret_cast<uint2*>(xbp + r * 512 + (((wchunk ^ (r & 15)) << 4) | woff)) = pk;
        }
    }

    // ---- GEMM machinery: A = Wt rows (L2), B = X rows (LDS, swizzled) ----
    const __hip_bfloat16* wbase = (const __hip_bfloat16*)nullptr;  // set per-GEMM
    const int arow = fh * 128 + l15;            // A feature row base (+ m*16)
    const unsigned char* xrow = xbp + l15 * 512;  // B row base (+ n*16*512)

    f32x4 acc[8][4];
    const f32x4 zero = {0.f, 0.f, 0.f, 0.f};

    auto run_gemm = [&](const __hip_bfloat16* __restrict__ Wt) {
        const __hip_bfloat16* wb = Wt + (size_t)arow * FDIM + hi4 * 8;
#pragma unroll
        for (int m = 0; m < 8; ++m)
#pragma unroll
            for (int n = 0; n < 4; ++n) acc[m][n] = zero;
#pragma unroll
        for (int k0 = 0; k0 < 8; ++k0) {
            bf16x8 wa[8];
#pragma unroll
            for (int m = 0; m < 8; ++m)
                wa[m] = *reinterpret_cast<const bf16x8*>(wb + m * 16 * FDIM + k0 * 32);
            bf16x8 xf[4];
            const int ch = ((((k0 << 2) | hi4) ^ l15) << 4);
#pragma unroll
            for (int n = 0; n < 4; ++n)
                xf[n] = *reinterpret_cast<const bf16x8*>(xrow + n * (16 * 512) + ch);
#pragma unroll
            for (int m = 0; m < 8; ++m)
#pragma unroll
                for (int n = 0; n < 4; ++n)
                    acc[m][n] =
                        __builtin_amdgcn_mfma_f32_16x16x32_bf16(wa[m], xf[n], acc[m][n], 0, 0, 0);
        }
    };

    __syncthreads();

    // ---- stage 1: y1^T = Wt1 . X^T ; X = bf16(swish2(y1)) ----
    run_gemm(Wt1);
    __syncthreads();
    {
        const int woff = (hi4 & 1) << 3;
#pragma unroll
        for (int m = 0; m < 8; ++m) {
            const int fm = fh * 128 + m * 16 + hi4 * 4;
            const float4 pa = *reinterpret_cast<const float4*>(a2g + fm);
            const float4 pb = *reinterpret_cast<const float4*>(be2g + fm);
            const int chunk = (fh << 4) + (m << 1) + (hi4 >> 1);
#pragma unroll
            for (int n = 0; n < 4; ++n) {
                f32x4 y = acc[m][n];
                const int r = n * 16 + l15;
                uint2 pk;
                pk.x = cvt_pk_bf16(pa.x * y[0] * fast_sigm(pb.x * y[0]),
                                   pa.y * y[1] * fast_sigm(pb.y * y[1]));
                pk.y = cvt_pk_bf16(pa.z * y[2] * fast_sigm(pb.z * y[2]),
                                   pa.w * y[3] * fast_sigm(pb.w * y[3]));
                *reinterpret_cast<uint2*>(xbp + r * 512 + (((chunk ^ l15) << 4) | woff)) = pk;
            }
        }
    }
    __syncthreads();

    // ---- stage 2: y2^T = Wt2 . X^T ; h = av + y2 ; X = bf16(swish3(h)) ----
    run_gemm(Wt2);
    float aln[4];
#pragma unroll
    for (int n = 0; n < 4; ++n) aln[n] = __shfl(aL_reg, n * 16 + l15, 64);
    __syncthreads();
    {
        const int woff = (hi4 & 1) << 3;
#pragma unroll
        for (int m = 0; m < 8; ++m) {
            const int fm = fh * 128 + m * 16 + hi4 * 4;
            const float4 pa = *reinterpret_cast<const float4*>(a3g + fm);
            const float4 pb = *reinterpret_cast<const float4*>(be3g + fm);
            const float4 pv = pos ? *reinterpret_cast<const float4*>(vp + fm)
                                  : *reinterpret_cast<const float4*>(vm + fm);
            const int chunk = (fh << 4) + (m << 1) + (hi4 >> 1);
#pragma unroll
            for (int n = 0; n < 4; ++n) {
                f32x4 y = acc[m][n];
                const int r = n * 16 + l15;
                float h0 = fmaf(aln[n], pv.x, y[0]);
                float h1 = fmaf(aln[n], pv.y, y[1]);
                float h2 = fmaf(aln[n], pv.z, y[2]);
                float h3 = fmaf(aln[n], pv.w, y[3]);
                uint2 pk;
                pk.x = cvt_pk_bf16(pa.x * h0 * fast_sigm(pb.x * h0),
                                   pa.y * h1 * fast_sigm(pb.y * h1));
                pk.y = cvt_pk_bf16(pa.z * h2 * fast_sigm(pb.z * h2),
                                   pa.w * h3 * fast_sigm(pb.w * h3));
                *reinterpret_cast<uint2*>(xbp + r * 512 + (((chunk ^ l15) << 4) | woff)) = pk;
            }
        }
    }
    __syncthreads();

    // ---- stage 3: out^T = Wt3 . X^T + b_out ----
    run_gemm(Wt3);
#pragma unroll
    for (int n = 0; n < 4; ++n) {
        float* orow = out + ((size_t)mol * NATOMS + n * 16 + l15) * FDIM;
#pragma unroll
        for (int m = 0; m < 8; ++m) {
            const int fm = fh * 128 + m * 16 + hi4 * 4;
            const float4 bb = *reinterpret_cast<const float4*>(b_out + fm);
            float4 r;
            r.x = acc[m][n][0] + bb.x;
            r.y = acc[m][n][1] + bb.y;
            r.z = acc[m][n][2] + bb.z;
            r.w = acc[m][n][3] + bb.w;
            *reinterpret_cast<float4*>(orow + fm) = r;
        }
    }
}

extern "C" void kernel_launch(void* const* d_in, const int* in_sizes, int n_in,
                              void* d_out, int out_size, void* d_ws, size_t ws_size,
                              hipStream_t stream) {
    const float* psi     = (const float*)d_in[0];
    const float* e_z     = (const float*)d_in[1];
    // d_in[2] = num_atoms (uniformly 64)
    const float* W_lin   = (const float*)d_in[3];
    const float* b_lin   = (const float*)d_in[4];
    const float* k_plus  = (const float*)d_in[5];
    const float* k_minus = (const float*)d_in[6];
    const float* v_plus  = (const float*)d_in[7];
    const float* v_minus = (const float*)d_in[8];
    const float* W_r1    = (const float*)d_in[9];
    const float* W_r2    = (const float*)d_in[10];
    const float* W_out   = (const float*)d_in[11];
    const float* b_out   = (const float*)d_in[12];
    const float* a1      = (const float*)d_in[13];
    const float* be1     = (const float*)d_in[14];
    const float* a2      = (const float*)d_in[15];
    const float* be2     = (const float*)d_in[16];
    const float* a3      = (const float*)d_in[17];
    const float* be3     = (const float*)d_in[18];
    float* out = (float*)d_out;

    char* ws = (char*)d_ws;
    float* wkp = (float*)ws;
    float* wkm = wkp + FDIM;
    float* bk2 = wkm + FDIM;
    __hip_bfloat16* Wt1 = (__hip_bfloat16*)(ws + 4096);
    __hip_bfloat16* Wt2 = Wt1 + FDIM * FDIM;
    __hip_bfloat16* Wt3 = Wt2 + FDIM * FDIM;

    const int n_mol = in_sizes[0];

    prep_wk<<<FDIM, FDIM, 0, stream>>>(W_lin, b_lin, k_plus, k_minus, wkp, wkm, bk2);
    prep_wt<<<3 * FDIM, FDIM, 0, stream>>>(W_r1, W_r2, W_out, Wt1, Wt2, Wt3);
    fused_ee<<<n_mol / 2, 256, 0, stream>>>(psi, e_z, wkp, wkm, bk2, v_plus, v_minus,
                                            Wt1, Wt2, Wt3, a1, be1, a2, be2, a3, be3,
                                            b_out, out);
}

// Round 8
// 308.096 us; speedup vs baseline: 1.0070x; 1.0070x over previous
//
#include <hip/hip_runtime.h>
#include <hip/hip_bf16.h>

#define FDIM 256
#define NATOMS 64

using bf16x8 = __attribute__((ext_vector_type(8))) short;
using f32x4  = __attribute__((ext_vector_type(4))) float;

__device__ __forceinline__ float fast_sigm(float x) {
    return __builtin_amdgcn_rcpf(1.0f + __expf(-x));
}
__device__ __forceinline__ unsigned cvt_pk_bf16(float lo, float hi) {
    unsigned r;
    asm("v_cvt_pk_bf16_f32 %0, %1, %2" : "=v"(r) : "v"(lo), "v"(hi));
    return r;
}

// ---------------- prep 1: wk± = W_lin @ k±, bk± = b_lin . k± ----------------
__global__ void prep_wk(const float* __restrict__ W_lin, const float* __restrict__ b_lin,
                        const float* __restrict__ kp, const float* __restrict__ km,
                        float* __restrict__ wkp, float* __restrict__ wkm,
                        float* __restrict__ bk2) {
    const int f = blockIdx.x;
    const int t = threadIdx.x;
    __shared__ float sp[FDIM], sm[FDIM];
    float w = W_lin[(size_t)f * FDIM + t];
    sp[t] = w * kp[t];
    sm[t] = w * km[t];
    __syncthreads();
    for (int s = 128; s > 0; s >>= 1) {
        if (t < s) { sp[t] += sp[t + s]; sm[t] += sm[t + s]; }
        __syncthreads();
    }
    if (t == 0) { wkp[f] = sp[0]; wkm[f] = sm[0]; }
    if (f == 0) {
        __syncthreads();
        sp[t] = b_lin[t] * kp[t];
        sm[t] = b_lin[t] * km[t];
        __syncthreads();
        for (int s = 128; s > 0; s >>= 1) {
            if (t < s) { sp[t] += sp[t + s]; sm[t] += sm[t + s]; }
            __syncthreads();
        }
        if (t == 0) { bk2[0] = sp[0]; bk2[1] = sm[0]; }
    }
}

// ---------------- prep 2: Wt[n][k] = bf16(W[k][n]) ----------------
__global__ void prep_wt(const float* __restrict__ W1, const float* __restrict__ W2,
                        const float* __restrict__ W3,
                        __hip_bfloat16* __restrict__ Wt1, __hip_bfloat16* __restrict__ Wt2,
                        __hip_bfloat16* __restrict__ Wt3) {
    const int b = blockIdx.x;
    const int mat = b >> 8;
    const int n = b & 255;
    const int k = threadIdx.x;
    const float* W = (mat == 0) ? W1 : (mat == 1) ? W2 : W3;
    __hip_bfloat16* Wt = (mat == 0) ? Wt1 : (mat == 1) ? Wt2 : Wt3;
    Wt[(size_t)n * FDIM + k] = __float2bfloat16(W[(size_t)k * FDIM + n]);
}

// ---------------- fused: 1 molecule / block, 4 waves ----------------
// Wave wv owns features [wv*64, wv*64+64) x all 64 atoms.
// X LDS XOR-swizzled (16B granule, chunk ^= row&15): 32.8KB -> 4 blocks/CU.
__global__ __launch_bounds__(256, 4) void fused_ee(
    const float* __restrict__ psi, const float* __restrict__ e_z,
    const float* __restrict__ wkp, const float* __restrict__ wkm,
    const float* __restrict__ bk2,
    const float* __restrict__ vp, const float* __restrict__ vm,
    const __hip_bfloat16* __restrict__ Wt1, const __hip_bfloat16* __restrict__ Wt2,
    const __hip_bfloat16* __restrict__ Wt3,
    const float* __restrict__ a1g, const float* __restrict__ be1g,
    const float* __restrict__ a2g, const float* __restrict__ be2g,
    const float* __restrict__ a3g, const float* __restrict__ be3g,
    const float* __restrict__ b_out, float* __restrict__ out) {

    // X[row][512B], swizzled: byte(row, 16B-chunk c, off) = row*512 + ((c ^ (row&15))<<4) + off
    __shared__ unsigned char Xb[NATOMS][512];
    __shared__ float nums[NATOMS];

    const int tid = threadIdx.x;
    const int lane = tid & 63;
    const int wv = tid >> 6;       // 0..3
    const int l15 = lane & 15;
    const int hi4 = lane >> 4;     // 0..3
    const int mol = blockIdx.x;
    const float psiv = psi[mol];
    const bool pos = (psiv >= 0.0f);
    unsigned char* xbp = &Xb[0][0];

    // ---- attention dots: lane owns (atom = wv*16+l15, feature-quarter q = hi4) ----
    // 64 FMA + 2 shfl per lane; no long shuffle chains.
    {
        const float4* ez4 = reinterpret_cast<const float4*>(e_z + (size_t)mol * NATOMS * FDIM);
        const float4* wk4 = reinterpret_cast<const float4*>(pos ? wkp : wkm);
        const float bk = pos ? bk2[0] : bk2[1];
        const int atom = wv * 16 + l15;
        const int qb = hi4 * 16;  // float4 index base of this lane's quarter
        float d0 = 0.f, d1 = 0.f;
#pragma unroll
        for (int i = 0; i < 16; i += 2) {
            const float4 e0 = ez4[(size_t)atom * 64 + qb + i];
            const float4 w0 = wk4[qb + i];
            const float4 e1 = ez4[(size_t)atom * 64 + qb + i + 1];
            const float4 w1 = wk4[qb + i + 1];
            d0 += e0.x * w0.x + e0.y * w0.y + e0.z * w0.z + e0.w * w0.w;
            d1 += e1.x * w1.x + e1.y * w1.y + e1.z * w1.z + e1.w * w1.w;
        }
        float d = d0 + d1;
        d += __shfl_xor(d, 16, 64);
        d += __shfl_xor(d, 32, 64);
        if (hi4 == 0) nums[atom] = (d + bk) * 0.0625f;
    }
    __syncthreads();

    // ---- redundant per-wave softmax: every wave computes all 64 a_i ----
    float aL_reg;  // a_i for atom == lane
    {
        float arg = nums[lane];
        float nv = fmaxf(arg, 0.0f) + log1pf(__expf(-fabsf(arg)));
        float s = nv;
#pragma unroll
        for (int off = 32; off > 0; off >>= 1) s += __shfl_xor(s, off, 64);
        aL_reg = psiv * nv * __builtin_amdgcn_rcpf(s);
    }

    // ---- stage-1 input: X[r][c] = bf16(swish1(a_r * v_c)), rows wv*16..+16 ----
    {
        const float4 v4  = pos ? reinterpret_cast<const float4*>(vp)[lane]
                               : reinterpret_cast<const float4*>(vm)[lane];
        const float4 a14 = reinterpret_cast<const float4*>(a1g)[lane];
        const float4 b14 = reinterpret_cast<const float4*>(be1g)[lane];
        const int wchunk = lane >> 1;      // 16B chunk of this lane's 8B write
        const int woff = (lane & 1) << 3;  // 8B half within chunk
#pragma unroll
        for (int i = 0; i < 16; ++i) {
            const int r = wv * 16 + i;
            const float al = __shfl(aL_reg, r, 64);
            float x0 = al * v4.x, x1 = al * v4.y, x2 = al * v4.z, x3 = al * v4.w;
            uint2 pk;
            pk.x = cvt_pk_bf16(a14.x * x0 * fast_sigm(b14.x * x0),
                               a14.y * x1 * fast_sigm(b14.y * x1));
            pk.y = cvt_pk_bf16(a14.z * x2 * fast_sigm(b14.z * x2),
                               a14.w * x3 * fast_sigm(b14.w * x3));
            *reinterpret_cast<uint2*>(xbp + r * 512 + (((wchunk ^ (r & 15)) << 4) | woff)) = pk;
        }
    }

    // ---- GEMM machinery: A = Wt rows (L2), B = X rows (LDS, swizzled) ----
    const int fbase = wv * 64 + l15;            // A-frag feature row (+ m*16)
    const int f0 = wv * 64 + hi4 * 4;           // C-frag feature base (+ m*16)
    const unsigned char* xrow = xbp + l15 * 512;

    f32x4 acc[4][4];
    const f32x4 zero = {0.f, 0.f, 0.f, 0.f};

    // 2-deep weight-fragment pipeline (R5's proven shape)
    auto run_gemm = [&](const __hip_bfloat16* __restrict__ Wt) {
        const __hip_bfloat16* wrow[4];
#pragma unroll
        for (int m = 0; m < 4; ++m) wrow[m] = Wt + (size_t)(fbase + m * 16) * FDIM + hi4 * 8;
#pragma unroll
        for (int m = 0; m < 4; ++m)
#pragma unroll
            for (int n = 0; n < 4; ++n) acc[m][n] = zero;
        bf16x8 wa[4], wn[4];
#pragma unroll
        for (int m = 0; m < 4; ++m) wa[m] = *reinterpret_cast<const bf16x8*>(wrow[m]);
#pragma unroll
        for (int k0 = 0; k0 < 8; ++k0) {
            if (k0 < 7) {
#pragma unroll
                for (int m = 0; m < 4; ++m)
                    wn[m] = *reinterpret_cast<const bf16x8*>(wrow[m] + (k0 + 1) * 32);
            }
            bf16x8 xf[4];
            const int ch = ((((k0 << 2) | hi4) ^ l15) << 4);
#pragma unroll
            for (int n = 0; n < 4; ++n)
                xf[n] = *reinterpret_cast<const bf16x8*>(xrow + n * (16 * 512) + ch);
#pragma unroll
            for (int m = 0; m < 4; ++m)
#pragma unroll
                for (int n = 0; n < 4; ++n)
                    acc[m][n] =
                        __builtin_amdgcn_mfma_f32_16x16x32_bf16(wa[m], xf[n], acc[m][n], 0, 0, 0);
#pragma unroll
            for (int m = 0; m < 4; ++m) wa[m] = wn[m];
        }
    };

    __syncthreads();

    // ---- stage 1: y1^T = Wt1 . X^T ; X = bf16(swish2(y1)) ----
    run_gemm(Wt1);
    float4 pa[4], pb[4];
#pragma unroll
    for (int m = 0; m < 4; ++m) {  // param-load latency overlaps barrier wait
        pa[m] = *reinterpret_cast<const float4*>(a2g + f0 + m * 16);
        pb[m] = *reinterpret_cast<const float4*>(be2g + f0 + m * 16);
    }
    __syncthreads();
    {
        const int woff = (hi4 & 1) << 3;
#pragma unroll
        for (int m = 0; m < 4; ++m) {
            const int chunk = (wv << 3) + (m << 1) + (hi4 >> 1);
#pragma unroll
            for (int n = 0; n < 4; ++n) {
                f32x4 y = acc[m][n];
                const int r = n * 16 + l15;
                uint2 pk;
                pk.x = cvt_pk_bf16(pa[m].x * y[0] * fast_sigm(pb[m].x * y[0]),
                                   pa[m].y * y[1] * fast_sigm(pb[m].y * y[1]));
                pk.y = cvt_pk_bf16(pa[m].z * y[2] * fast_sigm(pb[m].z * y[2]),
                                   pa[m].w * y[3] * fast_sigm(pb[m].w * y[3]));
                *reinterpret_cast<uint2*>(xbp + r * 512 + (((chunk ^ l15) << 4) | woff)) = pk;
            }
        }
    }
    __syncthreads();

    // ---- stage 2: y2^T = Wt2 . X^T ; h = av + y2 ; X = bf16(swish3(h)) ----
    run_gemm(Wt2);
    float4 pv[4];
#pragma unroll
    for (int m = 0; m < 4; ++m) {
        pa[m] = *reinterpret_cast<const float4*>(a3g + f0 + m * 16);
        pb[m] = *reinterpret_cast<const float4*>(be3g + f0 + m * 16);
        pv[m] = pos ? *reinterpret_cast<const float4*>(vp + f0 + m * 16)
                    : *reinterpret_cast<const float4*>(vm + f0 + m * 16);
    }
    float aln[4];
#pragma unroll
    for (int n = 0; n < 4; ++n) aln[n] = __shfl(aL_reg, n * 16 + l15, 64);
    __syncthreads();
    {
        const int woff = (hi4 & 1) << 3;
#pragma unroll
        for (int m = 0; m < 4; ++m) {
            const int chunk = (wv << 3) + (m << 1) + (hi4 >> 1);
#pragma unroll
            for (int n = 0; n < 4; ++n) {
                f32x4 y = acc[m][n];
                const int r = n * 16 + l15;
                float h0 = fmaf(aln[n], pv[m].x, y[0]);
                float h1 = fmaf(aln[n], pv[m].y, y[1]);
                float h2 = fmaf(aln[n], pv[m].z, y[2]);
                float h3 = fmaf(aln[n], pv[m].w, y[3]);
                uint2 pk;
                pk.x = cvt_pk_bf16(pa[m].x * h0 * fast_sigm(pb[m].x * h0),
                                   pa[m].y * h1 * fast_sigm(pb[m].y * h1));
                pk.y = cvt_pk_bf16(pa[m].z * h2 * fast_sigm(pb[m].z * h2),
                                   pa[m].w * h3 * fast_sigm(pb[m].w * h3));
                *reinterpret_cast<uint2*>(xbp + r * 512 + (((chunk ^ l15) << 4) | woff)) = pk;
            }
        }
    }
    __syncthreads();

    // ---- stage 3: out^T = Wt3 . X^T + b_out ; n-outer/m-inner fills 128B lines ----
    run_gemm(Wt3);
    float4 bbv[4];
#pragma unroll
    for (int m = 0; m < 4; ++m)
        bbv[m] = *reinterpret_cast<const float4*>(b_out + f0 + m * 16);
#pragma unroll
    for (int n = 0; n < 4; ++n) {
        float* orow = out + ((size_t)mol * NATOMS + n * 16 + l15) * FDIM + f0;
#pragma unroll
        for (int m = 0; m < 4; ++m) {
            float4 r;
            r.x = acc[m][n][0] + bbv[m].x;
            r.y = acc[m][n][1] + bbv[m].y;
            r.z = acc[m][n][2] + bbv[m].z;
            r.w = acc[m][n][3] + bbv[m].w;
            *reinterpret_cast<float4*>(orow + m * 16) = r;
        }
    }
}

extern "C" void kernel_launch(void* const* d_in, const int* in_sizes, int n_in,
                              void* d_out, int out_size, void* d_ws, size_t ws_size,
                              hipStream_t stream) {
    const float* psi     = (const float*)d_in[0];
    const float* e_z     = (const float*)d_in[1];
    // d_in[2] = num_atoms (uniformly 64)
    const float* W_lin   = (const float*)d_in[3];
    const float* b_lin   = (const float*)d_in[4];
    const float* k_plus  = (const float*)d_in[5];
    const float* k_minus = (const float*)d_in[6];
    const float* v_plus  = (const float*)d_in[7];
    const float* v_minus = (const float*)d_in[8];
    const float* W_r1    = (const float*)d_in[9];
    const float* W_r2    = (const float*)d_in[10];
    const float* W_out   = (const float*)d_in[11];
    const float* b_out   = (const float*)d_in[12];
    const float* a1      = (const float*)d_in[13];
    const float* be1     = (const float*)d_in[14];
    const float* a2      = (const float*)d_in[15];
    const float* be2     = (const float*)d_in[16];
    const float* a3      = (const float*)d_in[17];
    const float* be3     = (const float*)d_in[18];
    float* out = (float*)d_out;

    char* ws = (char*)d_ws;
    float* wkp = (float*)ws;
    float* wkm = wkp + FDIM;
    float* bk2 = wkm + FDIM;
    __hip_bfloat16* Wt1 = (__hip_bfloat16*)(ws + 4096);
    __hip_bfloat16* Wt2 = Wt1 + FDIM * FDIM;
    __hip_bfloat16* Wt3 = Wt2 + FDIM * FDIM;

    const int n_mol = in_sizes[0];

    prep_wk<<<FDIM, FDIM, 0, stream>>>(W_lin, b_lin, k_plus, k_minus, wkp, wkm, bk2);
    prep_wt<<<3 * FDIM, FDIM, 0, stream>>>(W_r1, W_r2, W_out, Wt1, Wt2, Wt3);
    fused_ee<<<n_mol, 256, 0, stream>>>(psi, e_z, wkp, wkm, bk2, v_plus, v_minus,
                                        Wt1, Wt2, Wt3, a1, be1, a2, be2, a3, be3,
                                        b_out, out);
}

// Round 9
// 226.305 us; speedup vs baseline: 1.3710x; 1.3614x over previous
//
#include <hip/hip_runtime.h>
#include <hip/hip_bf16.h>

#define FDIM 256
#define NATOMS 64

using bf16x8 = __attribute__((ext_vector_type(8))) short;
using f32x4  = __attribute__((ext_vector_type(4))) float;

__device__ __forceinline__ float fast_sigm(float x) {
    return __builtin_amdgcn_rcpf(1.0f + __expf(-x));
}
__device__ __forceinline__ unsigned cvt_pk_bf16(float lo, float hi) {
    unsigned r;
    asm("v_cvt_pk_bf16_f32 %0, %1, %2" : "=v"(r) : "v"(lo), "v"(hi));
    return r;
}

// ---------------- prep 1: wk± = W_lin @ k±, bk± = b_lin . k± ----------------
__global__ void prep_wk(const float* __restrict__ W_lin, const float* __restrict__ b_lin,
                        const float* __restrict__ kp, const float* __restrict__ km,
                        float* __restrict__ wkp, float* __restrict__ wkm,
                        float* __restrict__ bk2) {
    const int f = blockIdx.x;
    const int t = threadIdx.x;
    __shared__ float sp[FDIM], sm[FDIM];
    float w = W_lin[(size_t)f * FDIM + t];
    sp[t] = w * kp[t];
    sm[t] = w * km[t];
    __syncthreads();
    for (int s = 128; s > 0; s >>= 1) {
        if (t < s) { sp[t] += sp[t + s]; sm[t] += sm[t + s]; }
        __syncthreads();
    }
    if (t == 0) { wkp[f] = sp[0]; wkm[f] = sm[0]; }
    if (f == 0) {
        __syncthreads();
        sp[t] = b_lin[t] * kp[t];
        sm[t] = b_lin[t] * km[t];
        __syncthreads();
        for (int s = 128; s > 0; s >>= 1) {
            if (t < s) { sp[t] += sp[t + s]; sm[t] += sm[t + s]; }
            __syncthreads();
        }
        if (t == 0) { bk2[0] = sp[0]; bk2[1] = sm[0]; }
    }
}

// ---------------- prep 2: Wt[n][k] = bf16(W[k][n]) ----------------
__global__ void prep_wt(const float* __restrict__ W1, const float* __restrict__ W2,
                        const float* __restrict__ W3,
                        __hip_bfloat16* __restrict__ Wt1, __hip_bfloat16* __restrict__ Wt2,
                        __hip_bfloat16* __restrict__ Wt3) {
    const int b = blockIdx.x;
    const int mat = b >> 8;
    const int n = b & 255;
    const int k = threadIdx.x;
    const float* W = (mat == 0) ? W1 : (mat == 1) ? W2 : W3;
    __hip_bfloat16* Wt = (mat == 0) ? Wt1 : (mat == 1) ? Wt2 : Wt3;
    Wt[(size_t)n * FDIM + k] = __float2bfloat16(W[(size_t)k * FDIM + n]);
}

// ---------------- fused: 2 molecules / block, 8 waves (R6 structure) ----------------
// Wave wv owns features [wv*32, wv*32+32) x 64 atoms x 2 molecules.
// X in LDS XOR-swizzled (512B rows, 16B granule, chunk ^= row&15) -> conflict-free.
// Weight fragments: 2-deep pipeline extended ACROSS stages (k0 of stage s+1
// prefetched at the last k-step of stage s; lives through the epilogue).
__global__ __launch_bounds__(512, 4) void fused_ee(
    const float* __restrict__ psi, const float* __restrict__ e_z,
    const float* __restrict__ wkp, const float* __restrict__ wkm,
    const float* __restrict__ bk2,
    const float* __restrict__ vp, const float* __restrict__ vm,
    const __hip_bfloat16* __restrict__ Wt1, const __hip_bfloat16* __restrict__ Wt2,
    const __hip_bfloat16* __restrict__ Wt3,
    const float* __restrict__ a1g, const float* __restrict__ be1g,
    const float* __restrict__ a2g, const float* __restrict__ be2g,
    const float* __restrict__ a3g, const float* __restrict__ be3g,
    const float* __restrict__ b_out, float* __restrict__ out) {

    // Xb[p][row][512B], swizzled: byte(row, chunk c, off) = row*512 + ((c^(row&15))<<4) + off
    __shared__ unsigned char Xb[2][NATOMS][512];
    __shared__ float nums[2][NATOMS];

    const int tid = threadIdx.x;
    const int lane = tid & 63;
    const int wv = tid >> 6;       // 0..7
    const int l15 = lane & 15;
    const int hi4 = lane >> 4;     // 0..3
    const int mol0 = blockIdx.x * 2;
    const int mol1 = mol0 + 1;
    const float psv0 = psi[mol0], psv1 = psi[mol1];
    const bool pos0 = (psv0 >= 0.0f), pos1 = (psv1 >= 0.0f);
    unsigned char* xb0 = &Xb[0][0][0];
    unsigned char* xb1 = &Xb[1][0][0];

    // ---- attention dots: lane owns (mol = wv>>2, atom = (wv&3)*16+l15, quarter hi4) ----
    // 64 FMA + 2 shfl per lane; no long shuffle chains.
    {
        const int p_att = wv >> 2;
        const int molA = mol0 + p_att;
        const bool posA = p_att ? pos1 : pos0;
        const int atom = (wv & 3) * 16 + l15;
        const float4* ez4 = reinterpret_cast<const float4*>(e_z + (size_t)molA * NATOMS * FDIM);
        const float4* wk4 = reinterpret_cast<const float4*>(posA ? wkp : wkm);
        const float bk = posA ? bk2[0] : bk2[1];
        const int qb = hi4 * 16;
        float d0 = 0.f, d1 = 0.f;
#pragma unroll
        for (int i = 0; i < 16; i += 2) {
            const float4 e0 = ez4[(size_t)atom * 64 + qb + i];
            const float4 w0 = wk4[qb + i];
            const float4 e1 = ez4[(size_t)atom * 64 + qb + i + 1];
            const float4 w1 = wk4[qb + i + 1];
            d0 += e0.x * w0.x + e0.y * w0.y + e0.z * w0.z + e0.w * w0.w;
            d1 += e1.x * w1.x + e1.y * w1.y + e1.z * w1.z + e1.w * w1.w;
        }
        float d = d0 + d1;
        d += __shfl_xor(d, 16, 64);
        d += __shfl_xor(d, 32, 64);
        if (hi4 == 0) nums[p_att][atom] = (d + bk) * 0.0625f;
    }
    __syncthreads();

    // ---- redundant per-wave softmax for both molecules ----
    float aL0, aL1;  // a_i for atom == lane
    {
        float arg0 = nums[0][lane], arg1 = nums[1][lane];
        float nv0 = fmaxf(arg0, 0.0f) + log1pf(__expf(-fabsf(arg0)));
        float nv1 = fmaxf(arg1, 0.0f) + log1pf(__expf(-fabsf(arg1)));
        float s0 = nv0, s1 = nv1;
#pragma unroll
        for (int off = 32; off > 0; off >>= 1) {
            s0 += __shfl_xor(s0, off, 64);
            s1 += __shfl_xor(s1, off, 64);
        }
        aL0 = psv0 * nv0 * __builtin_amdgcn_rcpf(s0);
        aL1 = psv1 * nv1 * __builtin_amdgcn_rcpf(s1);
    }

    // ---- stage-1 input: X[p][r][c] = bf16(swish1(a_r * v_c)), rows wv*8..+8 ----
    {
        const float4 v40 = pos0 ? reinterpret_cast<const float4*>(vp)[lane]
                                : reinterpret_cast<const float4*>(vm)[lane];
        const float4 v41 = pos1 ? reinterpret_cast<const float4*>(vp)[lane]
                                : reinterpret_cast<const float4*>(vm)[lane];
        const float4 a14 = reinterpret_cast<const float4*>(a1g)[lane];
        const float4 b14 = reinterpret_cast<const float4*>(be1g)[lane];
        const int wchunk = lane >> 1;      // 16B chunk of this lane's 8B write
        const int woff = (lane & 1) << 3;  // 8B half within chunk
#pragma unroll
        for (int i = 0; i < 8; ++i) {
            const int r = wv * 8 + i;
            const float al0 = __shfl(aL0, r, 64);
            const float al1 = __shfl(aL1, r, 64);
            float x0 = al0 * v40.x, x1 = al0 * v40.y, x2 = al0 * v40.z, x3 = al0 * v40.w;
            float y0 = al1 * v41.x, y1 = al1 * v41.y, y2 = al1 * v41.z, y3 = al1 * v41.w;
            const int soff = r * 512 + (((wchunk ^ (r & 15)) << 4) | woff);
            uint2 pk0, pk1;
            pk0.x = cvt_pk_bf16(a14.x * x0 * fast_sigm(b14.x * x0),
                                a14.y * x1 * fast_sigm(b14.y * x1));
            pk0.y = cvt_pk_bf16(a14.z * x2 * fast_sigm(b14.z * x2),
                                a14.w * x3 * fast_sigm(b14.w * x3));
            pk1.x = cvt_pk_bf16(a14.x * y0 * fast_sigm(b14.x * y0),
                                a14.y * y1 * fast_sigm(b14.y * y1));
            pk1.y = cvt_pk_bf16(a14.z * y2 * fast_sigm(b14.z * y2),
                                a14.w * y3 * fast_sigm(b14.w * y3));
            *reinterpret_cast<uint2*>(xb0 + soff) = pk0;
            *reinterpret_cast<uint2*>(xb1 + soff) = pk1;
        }
    }

    // ---- GEMM machinery (R6 shape + swizzled X reads + cross-stage prefetch) ----
    const int fbase = wv * 32 + l15;   // A-frag feature row (+ m*16)
    const int kg = hi4 * 8;            // k sub-offset within 32-wide k-step
    const int f0 = wv * 32 + hi4 * 4;  // C-frag feature base (+ m*16)
    const unsigned char* xrow0 = xb0 + l15 * 512;
    const unsigned char* xrow1 = xb1 + l15 * 512;

    f32x4 acc[2][2][4];  // [mol][m][n]
    const f32x4 zero = {0.f, 0.f, 0.f, 0.f};
    bf16x8 wa0, wa1;     // current-k weight frags; live across epilogues

    // prime pipeline with Wt1 k0
    {
        const __hip_bfloat16* wb = Wt1 + (size_t)fbase * FDIM + kg;
        wa0 = *reinterpret_cast<const bf16x8*>(wb);
        wa1 = *reinterpret_cast<const bf16x8*>(wb + 16 * FDIM);
    }

    auto run_gemm = [&](const __hip_bfloat16* __restrict__ Wt,
                        const __hip_bfloat16* __restrict__ Wtn) {
        const __hip_bfloat16* wb = Wt + (size_t)fbase * FDIM + kg;
        const __hip_bfloat16* wbn = Wtn + (size_t)fbase * FDIM + kg;
#pragma unroll
        for (int p = 0; p < 2; ++p)
#pragma unroll
            for (int m = 0; m < 2; ++m)
#pragma unroll
                for (int n = 0; n < 4; ++n) acc[p][m][n] = zero;
#pragma unroll
        for (int k0 = 0; k0 < 8; ++k0) {
            bf16x8 wn0, wn1;
            if (k0 < 7) {
                wn0 = *reinterpret_cast<const bf16x8*>(wb + (k0 + 1) * 32);
                wn1 = *reinterpret_cast<const bf16x8*>(wb + 16 * FDIM + (k0 + 1) * 32);
            } else {  // cross-stage prefetch: next GEMM's k0 frags
                wn0 = *reinterpret_cast<const bf16x8*>(wbn);
                wn1 = *reinterpret_cast<const bf16x8*>(wbn + 16 * FDIM);
            }
            bf16x8 ba[4], bb[4];
            const int ch = ((((k0 << 2) | hi4) ^ l15) << 4);
#pragma unroll
            for (int n = 0; n < 4; ++n) {
                ba[n] = *reinterpret_cast<const bf16x8*>(xrow0 + n * (16 * 512) + ch);
                bb[n] = *reinterpret_cast<const bf16x8*>(xrow1 + n * (16 * 512) + ch);
            }
#pragma unroll
            for (int n = 0; n < 4; ++n) {
                acc[0][0][n] = __builtin_amdgcn_mfma_f32_16x16x32_bf16(wa0, ba[n], acc[0][0][n], 0, 0, 0);
                acc[0][1][n] = __builtin_amdgcn_mfma_f32_16x16x32_bf16(wa1, ba[n], acc[0][1][n], 0, 0, 0);
            }
#pragma unroll
            for (int n = 0; n < 4; ++n) {
                acc[1][0][n] = __builtin_amdgcn_mfma_f32_16x16x32_bf16(wa0, bb[n], acc[1][0][n], 0, 0, 0);
                acc[1][1][n] = __builtin_amdgcn_mfma_f32_16x16x32_bf16(wa1, bb[n], acc[1][1][n], 0, 0, 0);
            }
            wa0 = wn0;
            wa1 = wn1;
        }
    };

    __syncthreads();

    // ---- stage 1: y1^T = Wt1 . X^T ; X = bf16(swish2(y1)) ----
    run_gemm(Wt1, Wt2);
    float4 pa[2], pb[2];
#pragma unroll
    for (int m = 0; m < 2; ++m) {  // param-load latency overlaps barrier wait
        pa[m] = *reinterpret_cast<const float4*>(a2g + f0 + m * 16);
        pb[m] = *reinterpret_cast<const float4*>(be2g + f0 + m * 16);
    }
    __syncthreads();
    {
        const int woff = (hi4 & 1) << 3;
#pragma unroll
        for (int p = 0; p < 2; ++p) {
            unsigned char* xbp = p ? xb1 : xb0;
#pragma unroll
            for (int m = 0; m < 2; ++m) {
                const int chunk = (wv << 2) + (m << 1) + (hi4 >> 1);
#pragma unroll
                for (int n = 0; n < 4; ++n) {
                    f32x4 y = acc[p][m][n];
                    const int r = n * 16 + l15;
                    uint2 pk;
                    pk.x = cvt_pk_bf16(pa[m].x * y[0] * fast_sigm(pb[m].x * y[0]),
                                       pa[m].y * y[1] * fast_sigm(pb[m].y * y[1]));
                    pk.y = cvt_pk_bf16(pa[m].z * y[2] * fast_sigm(pb[m].z * y[2]),
                                       pa[m].w * y[3] * fast_sigm(pb[m].w * y[3]));
                    *reinterpret_cast<uint2*>(xbp + r * 512 + (((chunk ^ l15) << 4) | woff)) = pk;
                }
            }
        }
    }
    __syncthreads();

    // ---- stage 2: y2^T = Wt2 . X^T ; h = av + y2 ; X = bf16(swish3(h)) ----
    run_gemm(Wt2, Wt3);
    float4 pv0[2], pv1[2];
#pragma unroll
    for (int m = 0; m < 2; ++m) {
        pa[m] = *reinterpret_cast<const float4*>(a3g + f0 + m * 16);
        pb[m] = *reinterpret_cast<const float4*>(be3g + f0 + m * 16);
        pv0[m] = pos0 ? *reinterpret_cast<const float4*>(vp + f0 + m * 16)
                      : *reinterpret_cast<const float4*>(vm + f0 + m * 16);
        pv1[m] = pos1 ? *reinterpret_cast<const float4*>(vp + f0 + m * 16)
                      : *reinterpret_cast<const float4*>(vm + f0 + m * 16);
    }
    float aln0[4], aln1[4];
#pragma unroll
    for (int n = 0; n < 4; ++n) {
        aln0[n] = __shfl(aL0, n * 16 + l15, 64);
        aln1[n] = __shfl(aL1, n * 16 + l15, 64);
    }
    __syncthreads();
    {
        const int woff = (hi4 & 1) << 3;
#pragma unroll
        for (int p = 0; p < 2; ++p) {
            unsigned char* xbp = p ? xb1 : xb0;
#pragma unroll
            for (int m = 0; m < 2; ++m) {
                const int chunk = (wv << 2) + (m << 1) + (hi4 >> 1);
                const float4 pv = p ? pv1[m] : pv0[m];
#pragma unroll
                for (int n = 0; n < 4; ++n) {
                    const float al = p ? aln1[n] : aln0[n];
                    f32x4 y = acc[p][m][n];
                    const int r = n * 16 + l15;
                    float h0 = fmaf(al, pv.x, y[0]);
                    float h1 = fmaf(al, pv.y, y[1]);
                    float h2 = fmaf(al, pv.z, y[2]);
                    float h3 = fmaf(al, pv.w, y[3]);
                    uint2 pk;
                    pk.x = cvt_pk_bf16(pa[m].x * h0 * fast_sigm(pb[m].x * h0),
                                       pa[m].y * h1 * fast_sigm(pb[m].y * h1));
                    pk.y = cvt_pk_bf16(pa[m].z * h2 * fast_sigm(pb[m].z * h2),
                                       pa[m].w * h3 * fast_sigm(pb[m].w * h3));
                    *reinterpret_cast<uint2*>(xbp + r * 512 + (((chunk ^ l15) << 4) | woff)) = pk;
                }
            }
        }
    }
    __syncthreads();

    // ---- stage 3: out^T = Wt3 . X^T + b_out ; n-outer/m-inner fills 128B lines ----
    run_gemm(Wt3, Wt3);
    float4 bbv[2];
#pragma unroll
    for (int m = 0; m < 2; ++m)
        bbv[m] = *reinterpret_cast<const float4*>(b_out + f0 + m * 16);
#pragma unroll
    for (int p = 0; p < 2; ++p) {
        const int mol = p ? mol1 : mol0;
#pragma unroll
        for (int n = 0; n < 4; ++n) {
            float* orow = out + ((size_t)mol * NATOMS + n * 16 + l15) * FDIM + f0;
#pragma unroll
            for (int m = 0; m < 2; ++m) {
                float4 r;
                r.x = acc[p][m][n][0] + bbv[m].x;
                r.y = acc[p][m][n][1] + bbv[m].y;
                r.z = acc[p][m][n][2] + bbv[m].z;
                r.w = acc[p][m][n][3] + bbv[m].w;
                *reinterpret_cast<float4*>(orow + m * 16) = r;
            }
        }
    }
}

extern "C" void kernel_launch(void* const* d_in, const int* in_sizes, int n_in,
                              void* d_out, int out_size, void* d_ws, size_t ws_size,
                              hipStream_t stream) {
    const float* psi     = (const float*)d_in[0];
    const float* e_z     = (const float*)d_in[1];
    // d_in[2] = num_atoms (uniformly 64)
    const float* W_lin   = (const float*)d_in[3];
    const float* b_lin   = (const float*)d_in[4];
    const float* k_plus  = (const float*)d_in[5];
    const float* k_minus = (const float*)d_in[6];
    const float* v_plus  = (const float*)d_in[7];
    const float* v_minus = (const float*)d_in[8];
    const float* W_r1    = (const float*)d_in[9];
    const float* W_r2    = (const float*)d_in[10];
    const float* W_out   = (const float*)d_in[11];
    const float* b_out   = (const float*)d_in[12];
    const float* a1      = (const float*)d_in[13];
    const float* be1     = (const float*)d_in[14];
    const float* a2      = (const float*)d_in[15];
    const float* be2     = (const float*)d_in[16];
    const float* a3      = (const float*)d_in[17];
    const float* be3     = (const float*)d_in[18];
    float* out = (float*)d_out;

    char* ws = (char*)d_ws;
    float* wkp = (float*)ws;
    float* wkm = wkp + FDIM;
    float* bk2 = wkm + FDIM;
    __hip_bfloat16* Wt1 = (__hip_bfloat16*)(ws + 4096);
    __hip_bfloat16* Wt2 = Wt1 + FDIM * FDIM;
    __hip_bfloat16* Wt3 = Wt2 + FDIM * FDIM;

    const int n_mol = in_sizes[0];

    prep_wk<<<FDIM, FDIM, 0, stream>>>(W_lin, b_lin, k_plus, k_minus, wkp, wkm, bk2);
    prep_wt<<<3 * FDIM, FDIM, 0, stream>>>(W_r1, W_r2, W_out, Wt1, Wt2, Wt3);
    fused_ee<<<n_mol / 2, 512, 0, stream>>>(psi, e_z, wkp, wkm, bk2, v_plus, v_minus,
                                            Wt1, Wt2, Wt3, a1, be1, a2, be2, a3, be3,
                                            b_out, out);
}